// Round 5
// baseline (307.316 us; speedup 1.0000x reference)
//
#include <hip/hip_runtime.h>
#include <hip/hip_bf16.h>
#include <cstdint>

#define B_   2
#define N_   1024
#define DN_  128
#define DE_  16
#define DG_  128
#define MID_ 64
#define OUT_ 128
#define TI_  2
#define PR_ROWS 4

typedef short bf16x8 __attribute__((ext_vector_type(8)));
typedef float f32x4  __attribute__((ext_vector_type(4)));

__device__ inline short f2bf(float f) {
    union { float f; unsigned u; } v; v.f = f;
    unsigned r = v.u + 0x7FFFu + ((v.u >> 16) & 1u);   // RTNE
    return (short)(unsigned short)(r >> 16);
}

__device__ inline unsigned pk2(float lo, float hi) {
    union { __hip_bfloat162 h; unsigned u; } p;
    p.h = __float22bfloat162_rn(make_float2(lo, hi));  // v_cvt_pk_bf16_f32
    return p.u;
}

// ---------------------------------------------------------------------------
// Fused prep kernel (unchanged — not the bottleneck).
// ---------------------------------------------------------------------------
__global__ void __launch_bounds__(384) prep_all(
    const float* __restrict__ features, const float* __restrict__ g_features,
    const float* __restrict__ Wm, const float* __restrict__ bm,
    const float* __restrict__ Wskip, const float* __restrict__ bskip,
    const float* __restrict__ W1, const float* __restrict__ b1,
    const float* __restrict__ W2, const float* __restrict__ b2,
    const float* __restrict__ We, const float* __restrict__ be,
    const float* __restrict__ Wg, const float* __restrict__ bg,
    float* __restrict__ values, float* __restrict__ skipo,
    float* __restrict__ P1x, float* __restrict__ p2,
    float* __restrict__ pg, short* __restrict__ We_frag)
{
    const int t   = threadIdx.x;
    const int blk = blockIdx.x;

    if (blk == 512) {                       // --- We fragment prep ---
        for (int e = t; e < 4 * 64 * 8; e += 384) {
            const int c    = e >> 9;
            const int lane = (e >> 3) & 63;
            const int j    = e & 7;
            const int quad = lane >> 4, s = lane & 15;
            short v = 0;
            if (quad < 2) v = f2bf(We[(quad * 8 + j) * MID_ + c * 16 + s]);
            We_frag[e] = v;
        }
        return;
    }
    if (blk == 513) {                       // --- pg ---
        if (t < MID_) {
            float a0 = bg[t], a1 = bg[t];
            for (int k = 0; k < DG_; ++k) {
                const float w = Wg[k * MID_ + t];
                a0 += g_features[k] * w;
                a1 += g_features[DG_ + k] * w;
            }
            pg[t] = a0; pg[MID_ + t] = a1;
        }
        return;
    }

    // --- per-node projections ---
    const int r0 = blk * PR_ROWS;
    __shared__ float feat[PR_ROWS][DN_];
    for (int idx = t; idx < PR_ROWS * DN_; idx += 384)
        feat[idx >> 7][idx & 127] = features[(size_t)r0 * DN_ + idx];
    __syncthreads();

    const float* W; int c, stride; float base; float* outp; int ostride;
    if (t < 128) {
        W = Wm;    c = t;       stride = OUT_; base = bm[c];
        outp = values + (size_t)r0 * OUT_ + c; ostride = OUT_;
    } else if (t < 256) {
        W = Wskip; c = t - 128; stride = OUT_; base = bskip[c];
        outp = skipo + (size_t)r0 * OUT_ + c;  ostride = OUT_;
    } else if (t < 320) {
        W = W1;    c = t - 256; stride = MID_; base = b1[c] + be[c];
        outp = P1x + (size_t)r0 * MID_ + c;    ostride = MID_;
    } else {
        W = W2;    c = t - 320; stride = MID_; base = b2[c];
        outp = p2 + (size_t)r0 * MID_ + c;     ostride = MID_;
    }

    float acc[PR_ROWS] = {};
    for (int k = 0; k < DN_; ++k) {
        const float w = W[k * stride + c];
        #pragma unroll
        for (int q = 0; q < PR_ROWS; ++q) acc[q] += feat[q][k] * w;
    }
    #pragma unroll
    for (int q = 0; q < PR_ROWS; ++q) outp[q * ostride] = acc[q] + base;
}

// ---------------------------------------------------------------------------
// k_logits: 2048 blocks x 256 threads. Each block computes a 2-row x 512-col
// patch of logits and writes raw fp32 logits to global.
// R4 post-mortem: intra-wave ILP didn't move VALUBusy (pinned ~38%); the
// monolithic 3-phase kernel was latency/phase-bound. Splitting lets this
// phase run at 8 blocks-of-work/CU with no downstream barriers.
// Inner math identical to R2's Pass A (1-deep e prefetch, bias in MFMA C).
// ---------------------------------------------------------------------------
__global__ void __launch_bounds__(256) k_logits(
    const float* __restrict__ e_features, const short* __restrict__ We_frag,
    const float* __restrict__ Wa, const float* __restrict__ P1x,
    const float* __restrict__ p2, const float* __restrict__ pg,
    float* __restrict__ lg)
{
    const int t    = threadIdx.x;
    const int wv   = t >> 6;                          // 0..3
    const int l    = t & 63;
    const int quad = l >> 4;
    const int s    = l & 15;
    const int r    = blockIdx.x;
    const int jb   = r & 1;                           // j half
    const int ri   = r >> 1;                          // 0..1023
    const int b    = ri >> 9;
    const int i0   = (ri & 511) * TI_;

    // ---- block constants ----
    bf16x8 bfr[4];
    float  wa_r[4], p2i[TI_][4];
    #pragma unroll
    for (int c = 0; c < 4; ++c) {
        bfr[c]  = *(const bf16x8*)&We_frag[(c * 64 + l) * 8];
        wa_r[c] = Wa[c * 16 + s];
        const float pgc = pg[b * MID_ + c * 16 + s];
        #pragma unroll
        for (int ii = 0; ii < TI_; ++ii)
            p2i[ii][c] = p2[((size_t)(b * N_ + i0 + ii)) * MID_ + c * 16 + s] + pgc;
    }
    const size_t erow0 = (size_t)(b * N_ + i0) * N_;
    const int jt0 = jb * 32;                          // first tile of this block

    // ---- 1-deep pipelined logits: wave wv owns tiles {jt0+wv+4*it} ----
    float4 eA[TI_][2];
    if (quad < 2) {
        #pragma unroll
        for (int ii = 0; ii < TI_; ++ii) {
            const float* ep = &e_features[(erow0 + (size_t)ii * N_ + (jt0 + wv) * 16 + s) * DE_ + quad * 8];
            eA[ii][0] = *(const float4*)ep;
            eA[ii][1] = *(const float4*)(ep + 4);
        }
    }
    for (int it = 0; it < 8; ++it) {
        const int tile = jt0 + wv + it * 4;
        const int j0   = tile * 16;

        unsigned af[TI_][4];
        #pragma unroll
        for (int ii = 0; ii < TI_; ++ii) {
            if (quad < 2) {
                af[ii][0] = pk2(eA[ii][0].x, eA[ii][0].y);
                af[ii][1] = pk2(eA[ii][0].z, eA[ii][0].w);
                af[ii][2] = pk2(eA[ii][1].x, eA[ii][1].y);
                af[ii][3] = pk2(eA[ii][1].z, eA[ii][1].w);
            } else {
                af[ii][0] = af[ii][1] = af[ii][2] = af[ii][3] = 0u;
            }
        }
        if (it < 7 && quad < 2) {
            const int jn = (tile + 4) * 16;
            #pragma unroll
            for (int ii = 0; ii < TI_; ++ii) {
                const float* ep = &e_features[(erow0 + (size_t)ii * N_ + jn + s) * DE_ + quad * 8];
                eA[ii][0] = *(const float4*)ep;
                eA[ii][1] = *(const float4*)(ep + 4);
            }
        }
        // P1x bias tile -> MFMA C-operand
        float bse[4][4];
        {
            const float* pb = &P1x[((size_t)(b * N_) + j0 + quad * 4) * MID_ + s];
            #pragma unroll
            for (int c = 0; c < 4; ++c)
                #pragma unroll
                for (int rr = 0; rr < 4; ++rr)
                    bse[c][rr] = pb[rr * MID_ + c * 16];
        }
        #pragma unroll
        for (int ii = 0; ii < TI_; ++ii) {
            union { unsigned u[4]; bf16x8 v; } a;
            a.u[0] = af[ii][0]; a.u[1] = af[ii][1];
            a.u[2] = af[ii][2]; a.u[3] = af[ii][3];
            f32x4 acc[4];
            #pragma unroll
            for (int c = 0; c < 4; ++c) {
                f32x4 cin;
                cin[0] = bse[c][0] + p2i[ii][c];
                cin[1] = bse[c][1] + p2i[ii][c];
                cin[2] = bse[c][2] + p2i[ii][c];
                cin[3] = bse[c][3] + p2i[ii][c];
                acc[c] = __builtin_amdgcn_mfma_f32_16x16x32_bf16(a.v, bfr[c], cin, 0, 0, 0);
            }
            float tt[4];
            #pragma unroll
            for (int rr = 0; rr < 4; ++rr) {
                float x0 = acc[0][rr], x1 = acc[1][rr], x2 = acc[2][rr], x3 = acc[3][rr];
                x0 = fmaxf(x0, 0.01f * x0);
                x1 = fmaxf(x1, 0.01f * x1);
                x2 = fmaxf(x2, 0.01f * x2);
                x3 = fmaxf(x3, 0.01f * x3);
                tt[rr] = x0 * wa_r[0] + x1 * wa_r[1] + x2 * wa_r[2] + x3 * wa_r[3];
            }
            #pragma unroll
            for (int o = 1; o < 16; o <<= 1) {
                tt[0] += __shfl_xor(tt[0], o);
                tt[1] += __shfl_xor(tt[1], o);
                tt[2] += __shfl_xor(tt[2], o);
                tt[3] += __shfl_xor(tt[3], o);
            }
            if (s < 4)
                lg[((size_t)(b * N_ + i0 + ii)) * N_ + j0 + quad * 4 + s] = tt[s];
        }
    }
}

// ---------------------------------------------------------------------------
// k_attn: 1024 blocks x 256 threads, TI=2 i-rows/block.
// Masked softmax (logits from global, L2/L3-hot) + coefs@values + skip+relu.
// Structure = R2's Pass B/C verbatim.
// ---------------------------------------------------------------------------
__global__ void __launch_bounds__(256) k_attn(
    const float* __restrict__ lg, const float* __restrict__ adj,
    const float* __restrict__ values, const float* __restrict__ skipo,
    float* __restrict__ out)
{
    const int t  = threadIdx.x;
    const int wv = t >> 6;                            // 0..3
    const int l  = t & 63;
    const int r  = blockIdx.x;
    const int b  = (r >> 2) & 1;                      // XCD r%8 -> one batch
    const int i0 = (((r >> 3) << 2) | (r & 3)) * TI_;

    __shared__ float lgP[TI_][N_];
    __shared__ float redv[4][16][20];
    __shared__ float sinv[TI_];
    __shared__ float pmax[4];
    __shared__ float psum[4];

    // ---- masked softmax: wave wv owns row (wv&1), half (wv>>1) ----
    {
        const int rw = wv & 1, h = wv >> 1;
        const int c0 = h * 512 + l * 4;
        const float* lrow = &lg[(size_t)(b * N_ + i0 + rw) * N_];
        const size_t arb  = (size_t)(b * N_ + i0 + rw) * N_;
        float4 lv[2], av[2];
        #pragma unroll
        for (int q = 0; q < 2; ++q) {
            lv[q] = *(const float4*)&lrow[c0 + 256 * q];
            av[q] = *(const float4*)&adj[arb + c0 + 256 * q];
        }
        const float NEG = -3.4e38f;
        float m = NEG;
        #pragma unroll
        for (int q = 0; q < 2; ++q) {
            m = fmaxf(m, av[q].x > 0.f ? lv[q].x : NEG);
            m = fmaxf(m, av[q].y > 0.f ? lv[q].y : NEG);
            m = fmaxf(m, av[q].z > 0.f ? lv[q].z : NEG);
            m = fmaxf(m, av[q].w > 0.f ? lv[q].w : NEG);
        }
        #pragma unroll
        for (int o = 1; o < 64; o <<= 1) m = fmaxf(m, __shfl_xor(m, o));
        if (l == 0) pmax[wv] = m;
        __syncthreads();
        m = fmaxf(pmax[rw], pmax[2 + rw]);
        float sum = 0.f;
        #pragma unroll
        for (int q = 0; q < 2; ++q) {
            float4 e4;
            e4.x = av[q].x > 0.f ? __expf(lv[q].x - m) : 0.f;
            e4.y = av[q].y > 0.f ? __expf(lv[q].y - m) : 0.f;
            e4.z = av[q].z > 0.f ? __expf(lv[q].z - m) : 0.f;
            e4.w = av[q].w > 0.f ? __expf(lv[q].w - m) : 0.f;
            *(float4*)&lgP[rw][c0 + 256 * q] = e4;
            sum += (e4.x + e4.y) + (e4.z + e4.w);
        }
        #pragma unroll
        for (int o = 1; o < 64; o <<= 1) sum += __shfl_xor(sum, o);
        if (l == 0) psum[wv] = sum;
        __syncthreads();
        if (t < TI_) sinv[t] = 1.0f / (psum[t] + psum[t + 2]);
        // lgP exp-writes are pre-psum-barrier; sinv read after redv barrier.
    }

    // ---- (exp @ values) shared across the 2 i-rows ----
    const int cg = l & 15, jp = l >> 4, ch0 = cg * 8;
    float acc[TI_][8] = {};
    const float* vb = values + (size_t)b * N_ * OUT_ + ch0;
    for (int k = 0; k < 64; ++k) {
        const int j = wv * 4 + jp + k * 16;
        float cw[TI_];
        #pragma unroll
        for (int ii = 0; ii < TI_; ++ii) cw[ii] = lgP[ii][j];
        const float* vp = vb + (size_t)j * OUT_;
        const float4 v0 = *(const float4*)vp;
        const float4 v1 = *(const float4*)(vp + 4);
        const float vv[8] = {v0.x, v0.y, v0.z, v0.w, v1.x, v1.y, v1.z, v1.w};
        #pragma unroll
        for (int ii = 0; ii < TI_; ++ii)
            #pragma unroll
            for (int kk = 0; kk < 8; ++kk)
                acc[ii][kk] += cw[ii] * vv[kk];
    }
    #pragma unroll
    for (int ii = 0; ii < TI_; ++ii)
        #pragma unroll
        for (int kk = 0; kk < 8; ++kk) {
            acc[ii][kk] += __shfl_xor(acc[ii][kk], 16);
            acc[ii][kk] += __shfl_xor(acc[ii][kk], 32);
        }
    if (l < 16) {
        #pragma unroll
        for (int ii = 0; ii < TI_; ++ii)
            #pragma unroll
            for (int q = 0; q < 2; ++q) {
                float4 w4 = make_float4(acc[ii][q * 4], acc[ii][q * 4 + 1],
                                        acc[ii][q * 4 + 2], acc[ii][q * 4 + 3]);
                *(float4*)&redv[wv][l][ii * 8 + q * 4] = w4;
            }
    }
    __syncthreads();
    {
        const int ch = t & 127, g = ch >> 3, kk = ch & 7;
        const int ii = t >> 7;                        // 0..1
        float sum = redv[0][g][ii * 8 + kk];
        #pragma unroll
        for (int w = 1; w < 4; ++w) sum += redv[w][g][ii * 8 + kk];
        const size_t ob = ((size_t)(b * N_ + i0 + ii)) * OUT_ + ch;
        out[ob] = fmaxf(sum * sinv[ii] + skipo[ob], 0.f);
    }
}

extern "C" void kernel_launch(void* const* d_in, const int* in_sizes, int n_in,
                              void* d_out, int out_size, void* d_ws, size_t ws_size,
                              hipStream_t stream) {
    const float* features   = (const float*)d_in[0];
    const float* e_features = (const float*)d_in[1];
    const float* g_features = (const float*)d_in[2];
    const float* adj        = (const float*)d_in[3];
    const float* Wm    = (const float*)d_in[4];
    const float* bm    = (const float*)d_in[5];
    const float* Wskip = (const float*)d_in[6];
    const float* bskip = (const float*)d_in[7];
    const float* W1    = (const float*)d_in[8];
    const float* b1    = (const float*)d_in[9];
    const float* W2    = (const float*)d_in[10];
    const float* b2    = (const float*)d_in[11];
    const float* We    = (const float*)d_in[12];
    const float* be    = (const float*)d_in[13];
    const float* Wg    = (const float*)d_in[14];
    const float* bg    = (const float*)d_in[15];
    const float* Wa    = (const float*)d_in[16];
    float* out = (float*)d_out;

    float* ws      = (float*)d_ws;
    float* values  = ws;                    // 262144 floats
    float* skipo   = ws + 262144;           // 262144
    float* P1x     = ws + 524288;           // 131072
    float* p2      = ws + 655360;           // 131072
    float* pg      = ws + 786432;           // 128
    short* We_frag = (short*)(ws + 786560); // 2048 shorts (1024 floats)
    float* lg      = ws + 787584;           // 2097152 floats (8 MB logits)

    prep_all<<<B_ * N_ / PR_ROWS + 2, 384, 0, stream>>>(
        features, g_features, Wm, bm, Wskip, bskip, W1, b1, W2, b2,
        We, be, Wg, bg, values, skipo, P1x, p2, pg, We_frag);
    k_logits<<<B_ * N_ / TI_ * 2, 256, 0, stream>>>(
        e_features, We_frag, Wa, P1x, p2, pg, lg);
    k_attn<<<B_ * N_ / TI_, 256, 0, stream>>>(
        lg, adj, values, skipo, out);
}

// Round 6
// 294.915 us; speedup vs baseline: 1.0421x; 1.0421x over previous
//
#include <hip/hip_runtime.h>
#include <hip/hip_bf16.h>
#include <cstdint>

#define B_   2
#define N_   1024
#define DN_  128
#define DE_  16
#define DG_  128
#define MID_ 64
#define OUT_ 128
#define TI_  2
#define PR_ROWS 4

typedef short bf16x8 __attribute__((ext_vector_type(8)));
typedef float f32x4  __attribute__((ext_vector_type(4)));

__device__ inline short f2bf(float f) {
    union { float f; unsigned u; } v; v.f = f;
    unsigned r = v.u + 0x7FFFu + ((v.u >> 16) & 1u);   // RTNE
    return (short)(unsigned short)(r >> 16);
}

__device__ inline unsigned pk2(float lo, float hi) {
    union { __hip_bfloat162 h; unsigned u; } p;
    p.h = __float22bfloat162_rn(make_float2(lo, hi));  // v_cvt_pk_bf16_f32
    return p.u;
}

// ---------------------------------------------------------------------------
// Fused prep kernel. P1x is now written TRANSPOSED (P1xT[mid][b*N+node]) so
// k_logits' j-dependent bias loads are lane-coalesced after the operand swap.
// ---------------------------------------------------------------------------
__global__ void __launch_bounds__(384) prep_all(
    const float* __restrict__ features, const float* __restrict__ g_features,
    const float* __restrict__ Wm, const float* __restrict__ bm,
    const float* __restrict__ Wskip, const float* __restrict__ bskip,
    const float* __restrict__ W1, const float* __restrict__ b1,
    const float* __restrict__ W2, const float* __restrict__ b2,
    const float* __restrict__ We, const float* __restrict__ be,
    const float* __restrict__ Wg, const float* __restrict__ bg,
    float* __restrict__ values, float* __restrict__ skipo,
    float* __restrict__ P1xT, float* __restrict__ p2,
    float* __restrict__ pg, short* __restrict__ We_frag)
{
    const int t   = threadIdx.x;
    const int blk = blockIdx.x;

    if (blk == 512) {                       // --- We fragment prep ---
        for (int e = t; e < 4 * 64 * 8; e += 384) {
            const int c    = e >> 9;
            const int lane = (e >> 3) & 63;
            const int j    = e & 7;
            const int quad = lane >> 4, s = lane & 15;
            short v = 0;
            if (quad < 2) v = f2bf(We[(quad * 8 + j) * MID_ + c * 16 + s]);
            We_frag[e] = v;
        }
        return;
    }
    if (blk == 513) {                       // --- pg ---
        if (t < MID_) {
            float a0 = bg[t], a1 = bg[t];
            for (int k = 0; k < DG_; ++k) {
                const float w = Wg[k * MID_ + t];
                a0 += g_features[k] * w;
                a1 += g_features[DG_ + k] * w;
            }
            pg[t] = a0; pg[MID_ + t] = a1;
        }
        return;
    }

    // --- per-node projections ---
    const int r0 = blk * PR_ROWS;
    __shared__ float feat[PR_ROWS][DN_];
    for (int idx = t; idx < PR_ROWS * DN_; idx += 384)
        feat[idx >> 7][idx & 127] = features[(size_t)r0 * DN_ + idx];
    __syncthreads();

    const float* W; int c, stride; float base; float* outp; int ostride;
    if (t < 128) {
        W = Wm;    c = t;       stride = OUT_; base = bm[c];
        outp = values + (size_t)r0 * OUT_ + c; ostride = OUT_;
    } else if (t < 256) {
        W = Wskip; c = t - 128; stride = OUT_; base = bskip[c];
        outp = skipo + (size_t)r0 * OUT_ + c;  ostride = OUT_;
    } else if (t < 320) {
        W = W1;    c = t - 256; stride = MID_; base = b1[c] + be[c];
        outp = P1xT + (size_t)c * (B_ * N_) + r0; ostride = 1;   // transposed
    } else {
        W = W2;    c = t - 320; stride = MID_; base = b2[c];
        outp = p2 + (size_t)r0 * MID_ + c;     ostride = MID_;
    }

    float acc[PR_ROWS] = {};
    for (int k = 0; k < DN_; ++k) {
        const float w = W[k * stride + c];
        #pragma unroll
        for (int q = 0; q < PR_ROWS; ++q) acc[q] += feat[q][k] * w;
    }
    #pragma unroll
    for (int q = 0; q < PR_ROWS; ++q) outp[q * ostride] = acc[q] + base;
}

// ---------------------------------------------------------------------------
// k_logits v2: operand-swapped MFMA. 2048 blocks x 256 threads.
// R5 post-mortem: bse loads fed the MFMA C-operand in-iteration (~200-600cy
// stall before every MFMA) and the MID-reduce cost 16 shuffles/tile.
// Swap: D = We_frag (A) x e_frag (B) -> D[mid, j]. Lane mappings of A-row
// and B-col are identical on gfx950, so NO repacking changes -- only the
// argument order. Now:
//  - each lane owns 16 MID channels of one j: reduce = 2 shuffles.
//  - i-bias (p2+pg) lives in registers as the MFMA C-operand (no load).
//  - j-bias (P1xT) is prefetched one tile ahead, consumed post-MFMA.
//  - e tiles prefetched 2-deep (covers ~600-900cy L3 latency).
// ---------------------------------------------------------------------------
__global__ void __launch_bounds__(256) k_logits(
    const float* __restrict__ e_features, const short* __restrict__ We_frag,
    const float* __restrict__ Wa, const float* __restrict__ P1xT,
    const float* __restrict__ p2, const float* __restrict__ pg,
    float* __restrict__ lg)
{
    const int t    = threadIdx.x;
    const int wv   = t >> 6;                          // 0..3
    const int l    = t & 63;
    const int quad = l >> 4;
    const int s    = l & 15;
    const int r    = blockIdx.x;
    const int jb   = r & 1;                           // j half
    const int ri   = r >> 1;                          // 0..1023
    const int b    = ri >> 9;
    const int i0   = (ri & 511) * TI_;

    // ---- block constants ----
    bf16x8 bfr[4];                                    // We^T A-fragments
    float  wa_l[4][4];                                // Wa[mid] for this lane's mids
    f32x4  p2l[TI_][4];                               // p2+pg as MFMA C-operand
    #pragma unroll
    for (int c = 0; c < 4; ++c) {
        bfr[c] = *(const bf16x8*)&We_frag[(c * 64 + l) * 8];
        #pragma unroll
        for (int rr = 0; rr < 4; ++rr)
            wa_l[c][rr] = Wa[c * 16 + quad * 4 + rr];
        const float4 pg4 = *(const float4*)&pg[b * MID_ + c * 16 + quad * 4];
        #pragma unroll
        for (int ii = 0; ii < TI_; ++ii) {
            const float4 p4 = *(const float4*)&p2[((size_t)(b * N_ + i0 + ii)) * MID_ + c * 16 + quad * 4];
            p2l[ii][c][0] = p4.x + pg4.x;
            p2l[ii][c][1] = p4.y + pg4.y;
            p2l[ii][c][2] = p4.z + pg4.z;
            p2l[ii][c][3] = p4.w + pg4.w;
        }
    }
    const size_t erow0 = (size_t)(b * N_ + i0) * N_;
    const int jt0 = jb * 32;                          // first tile of this block
    const float* p1b = P1xT + (size_t)(quad * 4) * (B_ * N_) + b * N_ + s;

    // ---- prologue: e 2-deep, bse 1-deep ----
    float4 eA0[TI_][2], eA1[TI_][2];
    float  bA[4][4], bB[4][4];
    if (quad < 2) {
        #pragma unroll
        for (int ii = 0; ii < TI_; ++ii) {
            const float* ep0 = &e_features[(erow0 + (size_t)ii * N_ + (jt0 + wv) * 16 + s) * DE_ + quad * 8];
            eA0[ii][0] = *(const float4*)ep0;
            eA0[ii][1] = *(const float4*)(ep0 + 4);
            const float* ep1 = &e_features[(erow0 + (size_t)ii * N_ + (jt0 + wv + 4) * 16 + s) * DE_ + quad * 8];
            eA1[ii][0] = *(const float4*)ep1;
            eA1[ii][1] = *(const float4*)(ep1 + 4);
        }
    }
    {
        const float* pb = p1b + (jt0 + wv) * 16;
        #pragma unroll
        for (int c = 0; c < 4; ++c)
            #pragma unroll
            for (int rr = 0; rr < 4; ++rr)
                bA[c][rr] = pb[(size_t)(c * 16 + rr) * (B_ * N_)];
    }

    auto do_tile = [&](float4 (&eAr)[TI_][2], float (&bC)[4][4], float (&bN)[4][4], int it) {
        const int tile = jt0 + wv + it * 4;
        const int j0   = tile * 16;

        // pack e -> B fragments
        unsigned af[TI_][4];
        #pragma unroll
        for (int ii = 0; ii < TI_; ++ii) {
            if (quad < 2) {
                af[ii][0] = pk2(eAr[ii][0].x, eAr[ii][0].y);
                af[ii][1] = pk2(eAr[ii][0].z, eAr[ii][0].w);
                af[ii][2] = pk2(eAr[ii][1].x, eAr[ii][1].y);
                af[ii][3] = pk2(eAr[ii][1].z, eAr[ii][1].w);
            } else {
                af[ii][0] = af[ii][1] = af[ii][2] = af[ii][3] = 0u;
            }
        }
        // refill this e-buffer for tile+8 (consumed two iterations later)
        if (it < 6 && quad < 2) {
            #pragma unroll
            for (int ii = 0; ii < TI_; ++ii) {
                const float* ep = &e_features[(erow0 + (size_t)ii * N_ + (size_t)(tile + 8) * 16 + s) * DE_ + quad * 8];
                eAr[ii][0] = *(const float4*)ep;
                eAr[ii][1] = *(const float4*)(ep + 4);
            }
        }
        // prefetch next tile's j-bias (consumed next iteration, post-MFMA)
        if (it < 7) {
            const float* pb = p1b + (tile + 4) * 16;
            #pragma unroll
            for (int c = 0; c < 4; ++c)
                #pragma unroll
                for (int rr = 0; rr < 4; ++rr)
                    bN[c][rr] = pb[(size_t)(c * 16 + rr) * (B_ * N_)];
        }
        #pragma unroll
        for (int ii = 0; ii < TI_; ++ii) {
            union { unsigned u[4]; bf16x8 v; } a;
            a.u[0] = af[ii][0]; a.u[1] = af[ii][1];
            a.u[2] = af[ii][2]; a.u[3] = af[ii][3];
            f32x4 acc[4];
            #pragma unroll
            for (int c = 0; c < 4; ++c)
                acc[c] = __builtin_amdgcn_mfma_f32_16x16x32_bf16(bfr[c], a.v, p2l[ii][c], 0, 0, 0);
            float part = 0.f;
            #pragma unroll
            for (int c = 0; c < 4; ++c)
                #pragma unroll
                for (int rr = 0; rr < 4; ++rr) {
                    float x = acc[c][rr] + bC[c][rr];
                    x = fmaxf(x, 0.01f * x);
                    part += x * wa_l[c][rr];
                }
            part += __shfl_xor(part, 16);
            part += __shfl_xor(part, 32);
            if (l < 16)
                lg[((size_t)(b * N_ + i0 + ii)) * N_ + j0 + l] = part;
        }
    };
    for (int it2 = 0; it2 < 8; it2 += 2) {
        do_tile(eA0, bA, bB, it2);
        do_tile(eA1, bB, bA, it2 + 1);
    }
}

// ---------------------------------------------------------------------------
// k_attn: 1024 blocks x 256 threads, TI=2 i-rows/block (unchanged from R5).
// ---------------------------------------------------------------------------
__global__ void __launch_bounds__(256) k_attn(
    const float* __restrict__ lg, const float* __restrict__ adj,
    const float* __restrict__ values, const float* __restrict__ skipo,
    float* __restrict__ out)
{
    const int t  = threadIdx.x;
    const int wv = t >> 6;                            // 0..3
    const int l  = t & 63;
    const int r  = blockIdx.x;
    const int b  = (r >> 2) & 1;                      // XCD r%8 -> one batch
    const int i0 = (((r >> 3) << 2) | (r & 3)) * TI_;

    __shared__ float lgP[TI_][N_];
    __shared__ float redv[4][16][20];
    __shared__ float sinv[TI_];
    __shared__ float pmax[4];
    __shared__ float psum[4];

    // ---- masked softmax: wave wv owns row (wv&1), half (wv>>1) ----
    {
        const int rw = wv & 1, h = wv >> 1;
        const int c0 = h * 512 + l * 4;
        const float* lrow = &lg[(size_t)(b * N_ + i0 + rw) * N_];
        const size_t arb  = (size_t)(b * N_ + i0 + rw) * N_;
        float4 lv[2], av[2];
        #pragma unroll
        for (int q = 0; q < 2; ++q) {
            lv[q] = *(const float4*)&lrow[c0 + 256 * q];
            av[q] = *(const float4*)&adj[arb + c0 + 256 * q];
        }
        const float NEG = -3.4e38f;
        float m = NEG;
        #pragma unroll
        for (int q = 0; q < 2; ++q) {
            m = fmaxf(m, av[q].x > 0.f ? lv[q].x : NEG);
            m = fmaxf(m, av[q].y > 0.f ? lv[q].y : NEG);
            m = fmaxf(m, av[q].z > 0.f ? lv[q].z : NEG);
            m = fmaxf(m, av[q].w > 0.f ? lv[q].w : NEG);
        }
        #pragma unroll
        for (int o = 1; o < 64; o <<= 1) m = fmaxf(m, __shfl_xor(m, o));
        if (l == 0) pmax[wv] = m;
        __syncthreads();
        m = fmaxf(pmax[rw], pmax[2 + rw]);
        float sum = 0.f;
        #pragma unroll
        for (int q = 0; q < 2; ++q) {
            float4 e4;
            e4.x = av[q].x > 0.f ? __expf(lv[q].x - m) : 0.f;
            e4.y = av[q].y > 0.f ? __expf(lv[q].y - m) : 0.f;
            e4.z = av[q].z > 0.f ? __expf(lv[q].z - m) : 0.f;
            e4.w = av[q].w > 0.f ? __expf(lv[q].w - m) : 0.f;
            *(float4*)&lgP[rw][c0 + 256 * q] = e4;
            sum += (e4.x + e4.y) + (e4.z + e4.w);
        }
        #pragma unroll
        for (int o = 1; o < 64; o <<= 1) sum += __shfl_xor(sum, o);
        if (l == 0) psum[wv] = sum;
        __syncthreads();
        if (t < TI_) sinv[t] = 1.0f / (psum[t] + psum[t + 2]);
        // lgP exp-writes are pre-psum-barrier; sinv read after redv barrier.
    }

    // ---- (exp @ values) shared across the 2 i-rows ----
    const int cg = l & 15, jp = l >> 4, ch0 = cg * 8;
    float acc[TI_][8] = {};
    const float* vb = values + (size_t)b * N_ * OUT_ + ch0;
    for (int k = 0; k < 64; ++k) {
        const int j = wv * 4 + jp + k * 16;
        float cw[TI_];
        #pragma unroll
        for (int ii = 0; ii < TI_; ++ii) cw[ii] = lgP[ii][j];
        const float* vp = vb + (size_t)j * OUT_;
        const float4 v0 = *(const float4*)vp;
        const float4 v1 = *(const float4*)(vp + 4);
        const float vv[8] = {v0.x, v0.y, v0.z, v0.w, v1.x, v1.y, v1.z, v1.w};
        #pragma unroll
        for (int ii = 0; ii < TI_; ++ii)
            #pragma unroll
            for (int kk = 0; kk < 8; ++kk)
                acc[ii][kk] += cw[ii] * vv[kk];
    }
    #pragma unroll
    for (int ii = 0; ii < TI_; ++ii)
        #pragma unroll
        for (int kk = 0; kk < 8; ++kk) {
            acc[ii][kk] += __shfl_xor(acc[ii][kk], 16);
            acc[ii][kk] += __shfl_xor(acc[ii][kk], 32);
        }
    if (l < 16) {
        #pragma unroll
        for (int ii = 0; ii < TI_; ++ii)
            #pragma unroll
            for (int q = 0; q < 2; ++q) {
                float4 w4 = make_float4(acc[ii][q * 4], acc[ii][q * 4 + 1],
                                        acc[ii][q * 4 + 2], acc[ii][q * 4 + 3]);
                *(float4*)&redv[wv][l][ii * 8 + q * 4] = w4;
            }
    }
    __syncthreads();
    {
        const int ch = t & 127, g = ch >> 3, kk = ch & 7;
        const int ii = t >> 7;                        // 0..1
        float sum = redv[0][g][ii * 8 + kk];
        #pragma unroll
        for (int w = 1; w < 4; ++w) sum += redv[w][g][ii * 8 + kk];
        const size_t ob = ((size_t)(b * N_ + i0 + ii)) * OUT_ + ch;
        out[ob] = fmaxf(sum * sinv[ii] + skipo[ob], 0.f);
    }
}

extern "C" void kernel_launch(void* const* d_in, const int* in_sizes, int n_in,
                              void* d_out, int out_size, void* d_ws, size_t ws_size,
                              hipStream_t stream) {
    const float* features   = (const float*)d_in[0];
    const float* e_features = (const float*)d_in[1];
    const float* g_features = (const float*)d_in[2];
    const float* adj        = (const float*)d_in[3];
    const float* Wm    = (const float*)d_in[4];
    const float* bm    = (const float*)d_in[5];
    const float* Wskip = (const float*)d_in[6];
    const float* bskip = (const float*)d_in[7];
    const float* W1    = (const float*)d_in[8];
    const float* b1    = (const float*)d_in[9];
    const float* W2    = (const float*)d_in[10];
    const float* b2    = (const float*)d_in[11];
    const float* We    = (const float*)d_in[12];
    const float* be    = (const float*)d_in[13];
    const float* Wg    = (const float*)d_in[14];
    const float* bg    = (const float*)d_in[15];
    const float* Wa    = (const float*)d_in[16];
    float* out = (float*)d_out;

    float* ws      = (float*)d_ws;
    float* values  = ws;                    // 262144 floats
    float* skipo   = ws + 262144;           // 262144
    float* P1xT    = ws + 524288;           // 131072 (64 x 2048, transposed)
    float* p2      = ws + 655360;           // 131072
    float* pg      = ws + 786432;           // 128
    short* We_frag = (short*)(ws + 786560); // 2048 shorts (1024 floats)
    float* lg      = ws + 787584;           // 2097152 floats (8 MB logits)

    prep_all<<<B_ * N_ / PR_ROWS + 2, 384, 0, stream>>>(
        features, g_features, Wm, bm, Wskip, bskip, W1, b1, W2, b2,
        We, be, Wg, bg, values, skipo, P1xT, p2, pg, We_frag);
    k_logits<<<B_ * N_ / TI_ * 2, 256, 0, stream>>>(
        e_features, We_frag, Wa, P1xT, p2, pg, lg);
    k_attn<<<B_ * N_ / TI_, 256, 0, stream>>>(
        lg, adj, values, skipo, out);
}